// Round 15
// baseline (189.989 us; speedup 1.0000x reference)
//
#include <hip/hip_runtime.h>

#define DIM  128
#define BINS 1024

typedef __attribute__((ext_vector_type(8))) _Float16 f16x8;
typedef __attribute__((ext_vector_type(4))) float f32x4;

#define MFMA16(a, b, c) __builtin_amdgcn_mfma_f32_16x16x32_f16(a, b, c, 0, 0, 0)

#define GLDS(gp, lp) __builtin_amdgcn_global_load_lds(                        \
    (const __attribute__((address_space(1))) void*)(gp),                     \
    (__attribute__((address_space(3))) void*)(lp), 16, 0, 0)

// guaranteed single-instruction v_med3_f32
__device__ __forceinline__ float med3a(float a, float b, float c) {
    float r;
    asm("v_med3_f32 %0, %1, %2, %3" : "=v"(r) : "v"(a), "v"(b), "v"(c));
    return r;
}

// (key & ~0x1FF) | pair_id  — single v_and_or_b32
__device__ __forceinline__ float packkey(float k, int pid) {
    float r;
    asm("v_and_or_b32 %0, %1, %2, %3"
        : "=v"(r) : "v"(k), "s"(0xFFFFFE00u), "v"(pid));
    return r;
}

// sorted-insert x into descending (S0>=S1>=S2>=S3): 1 max + 3 med3, depth 2
#define SINS(x, S0, S1, S2, S3) do {                                          \
        float n0_ = fmaxf(S0, (x));                                           \
        float n1_ = med3a((x), S0, S1);                                       \
        float n2_ = med3a((x), S1, S2);                                       \
        float n3_ = med3a((x), S2, S3);                                       \
        S0 = n0_; S1 = n1_; S2 = n2_; S3 = n3_;                               \
    } while (0)

// ---- prep: esq (round-1 1-chain fmaf), cinit = -esq/2, E -> swizzled fp16 ----
__global__ __launch_bounds__(256) void vq_prep(
    const float* __restrict__ embed, _Float16* __restrict__ ehs,
    float* __restrict__ esq_g, float* __restrict__ cinit_g)
{
    int b = blockIdx.x * 256 + threadIdx.x;  // grid exactly BINS/256
    const float* e = embed + (size_t)b * DIM;
    float s = 0.f;
    #pragma unroll
    for (int k = 0; k < DIM; ++k) s = fmaf(e[k], e[k], s);
    esq_g[b] = s;
    cinit_g[b] = -0.5f * s;                  // MFMA C-init: key = dot - esq/2
    #pragma unroll
    for (int c = 0; c < 16; ++c) {          // 16B chunks of the fp16 row
        int slot = c ^ (b & 15);            // XOR-swizzle baked into storage
        #pragma unroll
        for (int j = 0; j < 8; ++j)
            ehs[b * 128 + slot * 8 + j] = (_Float16)e[c * 8 + j];   // RNE
    }
}

// ---- stage A: 1-term fp16 MFMA (C-init = -esq/2) + top-4 PAIR candidates ----
// 1024 thr = 16 waves, 1 block/CU (128 KB LDS). TWO mega-phases of 8 slabs:
// stage 128 KB -> barrier -> 32 barrier-free tiles (waves drift, MFMA/VALU of
// different waves overlap). 3 barriers/kernel vs 32 in round 14.
__global__ __launch_bounds__(1024, 1) void vq_stage_a(
    const float* __restrict__ x,
    const _Float16* __restrict__ ehs_g,
    const float* __restrict__ cinit_g,
    float* __restrict__ cand)               // [N][4] candidate PAIR bases
{
    __shared__ _Float16 ehb[65536];         // 128 KB: 8 slabs x 16 KB

    const int tid  = threadIdx.x;
    const int lane = tid & 63;
    const int li   = lane & 15;
    const int g    = lane >> 4;
    const int w    = tid >> 6;              // wave 0..15

    // X fragments fp16 (rows rowA, rowA+16) — 32 VGPR, const-indexed
    f16x8 xh[2][4];
    const size_t rowA = (size_t)blockIdx.x * 512 + w * 32 + li;
    #pragma unroll
    for (int rs = 0; rs < 2; ++rs) {
        const float* xp = x + (rowA + rs * 16) * DIM + g * 8;
        #pragma unroll
        for (int s = 0; s < 4; ++s) {
            float4 v0 = *(const float4*)(xp + s * 32);
            float4 v1 = *(const float4*)(xp + s * 32 + 4);
            f16x8 h;
            h[0] = (_Float16)v0.x; h[1] = (_Float16)v0.y;
            h[2] = (_Float16)v0.z; h[3] = (_Float16)v0.w;
            h[4] = (_Float16)v1.x; h[5] = (_Float16)v1.y;
            h[6] = (_Float16)v1.z; h[7] = (_Float16)v1.w;
            xh[rs][s] = h;
        }
    }

    // hoisted per-lane LDS byte offsets (loop-invariant swizzle addressing)
    int off0 = li * 256 + (((g + 0)  ^ li) << 4);
    int off1 = li * 256 + (((g + 4)  ^ li) << 4);
    int off2 = li * 256 + (((g + 8)  ^ li) << 4);
    int off3 = li * 256 + (((g + 12) ^ li) << 4);
    const float* cip = cinit_g + g * 4;     // ci quad base for this lane-group

    // top-4 packed pair-keys per rowset, descending
    const float NEG = __uint_as_float(0xFF7FFE00u);   // ~-3.4e38, low 9 bits 0
    float s0[2], s1[2], s2[2], s3[2];
    #pragma unroll
    for (int rs = 0; rs < 2; ++rs) { s0[rs] = s1[rs] = s2[rs] = s3[rs] = NEG; }

    for (int p = 0; p < 2; ++p) {
        if (p) __syncthreads();             // all waves done reading phase 0
        // stage this phase's 128 KB (8 slabs x 16 KB; 16B per thread per slab)
        {
            const char* gsrc = (const char*)ehs_g + (size_t)p * 131072;
            char* ldst = (char*)&ehb[0];
            int o = tid * 16;
            #pragma unroll
            for (int sl = 0; sl < 8; ++sl)
                GLDS(gsrc + sl * 16384 + o, ldst + sl * 16384 + o);
        }
        asm volatile("s_waitcnt vmcnt(0)" ::: "memory");
        __syncthreads();

        #pragma unroll 4
        for (int tt = 0; tt < 32; ++tt) {   // 32 tiles, NO barriers
            const int t = p * 32 + tt;
            const char* bE = (const char*)&ehb[0] + tt * 4096;
            f16x8 e0 = *(const f16x8*)(bE + off0);
            f16x8 e1 = *(const f16x8*)(bE + off1);
            f16x8 e2 = *(const f16x8*)(bE + off2);
            f16x8 e3 = *(const f16x8*)(bE + off3);
            const f32x4 ci = *(const f32x4*)(cip + t * 16);
            f32x4 aP0 = MFMA16(e0, xh[0][0], ci);
            f32x4 aP1 = MFMA16(e0, xh[1][0], ci);
            aP0 = MFMA16(e1, xh[0][1], aP0); aP1 = MFMA16(e1, xh[1][1], aP1);
            aP0 = MFMA16(e2, xh[0][2], aP0); aP1 = MFMA16(e2, xh[1][2], aP1);
            aP0 = MFMA16(e3, xh[0][3], aP0); aP1 = MFMA16(e3, xh[1][3], aP1);
            // fold: raw pair-max, pack 9-bit pair id, 2 sorted-inserts
            const int pid = t * 8 + g * 2;  // pair id of (binb, binb+1)
            {
                float q01 = packkey(fmaxf(aP0[0], aP0[1]), pid);
                float q23 = packkey(fmaxf(aP0[2], aP0[3]), pid + 1);
                SINS(q01, s0[0], s1[0], s2[0], s3[0]);
                SINS(q23, s0[0], s1[0], s2[0], s3[0]);
            }
            {
                float q01 = packkey(fmaxf(aP1[0], aP1[1]), pid);
                float q23 = packkey(fmaxf(aP1[2], aP1[3]), pid + 1);
                SINS(q01, s0[1], s1[1], s2[1], s3[1]);
                SINS(q23, s0[1], s1[1], s2[1], s3[1]);
            }
        }
    }

    // ---- merge the 4 lane-groups (disjoint pair sets, same rows) ----
    #pragma unroll
    for (int mm = 16; mm <= 32; mm <<= 1) {
        #pragma unroll
        for (int rs = 0; rs < 2; ++rs) {
            float q0 = __shfl_xor(s0[rs], mm);
            float q1 = __shfl_xor(s1[rs], mm);
            float q2 = __shfl_xor(s2[rs], mm);
            float q3 = __shfl_xor(s3[rs], mm);
            SINS(q0, s0[rs], s1[rs], s2[rs], s3[rs]);
            SINS(q1, s0[rs], s1[rs], s2[rs], s3[rs]);
            SINS(q2, s0[rs], s1[rs], s2[rs], s3[rs]);
            SINS(q3, s0[rs], s1[rs], s2[rs], s3[rs]);
        }
    }
    if (lane < 16) {
        #pragma unroll
        for (int rs = 0; rs < 2; ++rs) {
            const size_t r = rowA + rs * 16;
            // decode pair id -> pair base (even bin) — r12 rescore interface
            cand[r * 4 + 0] = (float)((__float_as_uint(s0[rs]) & 0x1FFu) << 1);
            cand[r * 4 + 1] = (float)((__float_as_uint(s1[rs]) & 0x1FFu) << 1);
            cand[r * 4 + 2] = (float)((__float_as_uint(s2[rs]) & 0x1FFu) << 1);
            cand[r * 4 + 3] = (float)((__float_as_uint(s3[rs]) & 0x1FFu) << 1);
        }
    }
}

// ---- rescore: exact fp32 on 4 pairs (8 bins); k split across 4 lanes ----
// Lane sub owns k-chunks (j*4+sub) -> every e/x load 64B-contiguous per
// 4-lane row-group. Butterfly shfl_xor sums bitwise lane-identical.
// Optionally fuses the gather (outq != nullptr).  [proven round 12]
__global__ __launch_bounds__(256) void vq_rescore(
    const float* __restrict__ x, const float* __restrict__ embed,
    const float* __restrict__ esq_g, const float* __restrict__ cand,
    float* __restrict__ ind_f, float4* __restrict__ outq)
{
    const int tid = threadIdx.x;
    const int sub = tid & 3;
    const size_t row = (size_t)blockIdx.x * 64 + (tid >> 2);

    const float4* xg = (const float4*)(x + row * DIM);
    float4 xq[8];
    #pragma unroll
    for (int j = 0; j < 8; ++j) xq[j] = xg[j * 4 + sub];   // 64B/row-group

    float xs = 0.f;
    #pragma unroll
    for (int j = 0; j < 8; ++j) {
        float4 v = xq[j];
        xs = fmaf(v.x, v.x, xs); xs = fmaf(v.y, v.y, xs);
        xs = fmaf(v.z, v.z, xs); xs = fmaf(v.w, v.w, xs);
    }
    xs += __shfl_xor(xs, 1);
    xs += __shfl_xor(xs, 2);

    const float4 qv = *(const float4*)&cand[row * 4];
    const int qb0 = (int)qv.x, qb1 = (int)qv.y, qb2 = (int)qv.z, qb3 = (int)qv.w;

    const float4* e4 = (const float4*)embed;
    f32x4 acc[8];
    #pragma unroll
    for (int c = 0; c < 8; ++c) acc[c] = f32x4{0.f,0.f,0.f,0.f};
    #pragma unroll
    for (int c = 0; c < 8; ++c) {           // all 64 loads independent
        const int bin = (c < 2 ? qb0 : c < 4 ? qb1 : c < 6 ? qb2 : qb3) + (c & 1);
        #pragma unroll
        for (int j = 0; j < 8; ++j) {
            float4 ev = e4[(size_t)bin * 32 + j * 4 + sub];
            float4 xv = xq[j];
            acc[c][0] = fmaf(xv.x, ev.x, acc[c][0]);
            acc[c][1] = fmaf(xv.y, ev.y, acc[c][1]);
            acc[c][2] = fmaf(xv.z, ev.z, acc[c][2]);
            acc[c][3] = fmaf(xv.w, ev.w, acc[c][3]);
        }
    }
    float bd = -3.402823466e38f;
    int   bb = 0x7FFFFFFF;
    #pragma unroll
    for (int c = 0; c < 8; ++c) {
        const int bin = (c < 2 ? qb0 : c < 4 ? qb1 : c < 6 ? qb2 : qb3) + (c & 1);
        float p = (acc[c][0] + acc[c][1]) + (acc[c][2] + acc[c][3]);
        p += __shfl_xor(p, 1);
        p += __shfl_xor(p, 2);               // full dot, lane-identical
        float d = -(fmaf(-2.f, p, xs) + esq_g[bin]);   // round-1 expression
        if (d > bd || (d == bd && bin < bb)) { bd = d; bb = bin; }
    }
    if (sub == 0) ind_f[row] = (float)bb;
    if (outq) {                              // fused gather (all lanes agree on bb)
        #pragma unroll
        for (int j = 0; j < 8; ++j)
            outq[row * 32 + j * 4 + sub] = e4[(size_t)bb * 32 + j * 4 + sub];
    }
}

// ---- gather (fallback path only): quantize = embed[ind] ----
__global__ __launch_bounds__(256) void vq_gather(
    const float* __restrict__ embed,
    const float* __restrict__ ind_f,
    float4* __restrict__ out)
{
    int i   = blockIdx.x * 256 + threadIdx.x;   // over N*DIM/4
    int row = i >> 5;                           // DIM/4 == 32
    int k   = i & 31;
    int b   = (int)ind_f[row];
    out[i] = reinterpret_cast<const float4*>(embed)[b * (DIM / 4) + k];
}

extern "C" void kernel_launch(void* const* d_in, const int* in_sizes, int n_in,
                              void* d_out, int out_size, void* d_ws, size_t ws_size,
                              hipStream_t stream) {
    const float* x     = (const float*)d_in[0];   // [N, 128] fp32
    const float* embed = (const float*)d_in[1];   // [1024, 128] fp32
    float* out = (float*)d_out;

    const int N = in_sizes[0] / DIM;              // 262144
    float* ind_f = out + (size_t)N * DIM;         // output 1 (indices as float)

    const bool use_ws = ws_size >= ((size_t)6 << 20);   // 4.27 MB needed
    _Float16* ehs; float* esq_g; float* cinit_g; float* cand;
    if (use_ws) {                                 // scratch fully in d_ws
        char* wb = (char*)d_ws;
        ehs     = (_Float16*)wb;                  // 256 KB
        esq_g   = (float*)(wb + (256u << 10));    // 4 KB
        cinit_g = (float*)(wb + (260u << 10));    // 4 KB
        cand    = (float*)(wb + (512u << 10));    // 4 MB
    } else {                                      // proven in-out layout
        char* ob = (char*)d_out;
        cand    = out;                            // [N][4] floats (4 MB)
        ehs     = (_Float16*)(ob + (32u << 20));
        esq_g   = (float*)(ob + (36u << 20));
        cinit_g = (float*)(ob + (36u << 20) + 4096);
    }

    vq_prep<<<BINS / 256, 256, 0, stream>>>(embed, ehs, esq_g, cinit_g);
    vq_stage_a<<<N / 512, 1024, 0, stream>>>(x, ehs, cinit_g, cand);
    vq_rescore<<<N / 64, 256, 0, stream>>>(x, embed, esq_g, cand, ind_f,
                                           use_ws ? (float4*)out : nullptr);
    if (!use_ws)
        vq_gather<<<(N * (DIM / 4)) / 256, 256, 0, stream>>>(embed, ind_f, (float4*)out);
}

// Round 16
// 189.077 us; speedup vs baseline: 1.0048x; 1.0048x over previous
//
#include <hip/hip_runtime.h>

#define DIM  128
#define BINS 1024

typedef __attribute__((ext_vector_type(8))) _Float16 f16x8;
typedef __attribute__((ext_vector_type(4))) float f32x4;

#define MFMA16(a, b, c) __builtin_amdgcn_mfma_f32_16x16x32_f16(a, b, c, 0, 0, 0)

#define GLDS(gp, lp) __builtin_amdgcn_global_load_lds(                        \
    (const __attribute__((address_space(1))) void*)(gp),                     \
    (__attribute__((address_space(3))) void*)(lp), 16, 0, 0)

// guaranteed single-instruction v_med3_f32
__device__ __forceinline__ float med3a(float a, float b, float c) {
    float r;
    asm("v_med3_f32 %0, %1, %2, %3" : "=v"(r) : "v"(a), "v"(b), "v"(c));
    return r;
}

// (key & ~0x1FF) | pair_id  — single v_and_or_b32
__device__ __forceinline__ float packkey(float k, int pid) {
    float r;
    asm("v_and_or_b32 %0, %1, %2, %3"
        : "=v"(r) : "v"(k), "s"(0xFFFFFE00u), "v"(pid));
    return r;
}

// sorted-insert x into descending (S0>=S1>=S2>=S3): 1 max + 3 med3, depth 2
#define SINS(x, S0, S1, S2, S3) do {                                          \
        float n0_ = fmaxf(S0, (x));                                           \
        float n1_ = med3a((x), S0, S1);                                       \
        float n2_ = med3a((x), S1, S2);                                       \
        float n3_ = med3a((x), S2, S3);                                       \
        S0 = n0_; S1 = n1_; S2 = n2_; S3 = n3_;                               \
    } while (0)

// ---- prep: esq (round-1 1-chain fmaf), cinit = -esq/2, E -> swizzled fp16 ----
__global__ __launch_bounds__(256) void vq_prep(
    const float* __restrict__ embed, _Float16* __restrict__ ehs,
    float* __restrict__ esq_g, float* __restrict__ cinit_g)
{
    int b = blockIdx.x * 256 + threadIdx.x;  // grid exactly BINS/256
    const float* e = embed + (size_t)b * DIM;
    float s = 0.f;
    #pragma unroll
    for (int k = 0; k < DIM; ++k) s = fmaf(e[k], e[k], s);
    esq_g[b] = s;
    cinit_g[b] = -0.5f * s;                  // MFMA C-init: key = dot - esq/2
    #pragma unroll
    for (int c = 0; c < 16; ++c) {          // 16B chunks of the fp16 row
        int slot = c ^ (b & 15);            // XOR-swizzle baked into storage
        #pragma unroll
        for (int j = 0; j < 8; ++j)
            ehs[b * 128 + slot * 8 + j] = (_Float16)e[c * 8 + j];   // RNE
    }
}

// ---- stage A: 1-term fp16 MFMA (C-init = -esq/2) + top-4 PAIR candidates ----
// r14 structure (256 thr = 4 waves, 16 steps x 64 bins, 36 KB LDS) with:
// hoisted swizzle offsets + pair-max-before-pack fold (12 VALU/rowset-tile).
__global__ __launch_bounds__(256) void vq_stage_a(
    const float* __restrict__ x,
    const _Float16* __restrict__ ehs_g,
    const float* __restrict__ cinit_g,
    float* __restrict__ cand)               // [N][4] candidate PAIR bases
{
    __shared__ _Float16 ehb[2][8192];       // 2 x 16 KB (64 bins x 128 fp16)
    __shared__ float ci_lds[BINS];          // 4 KB (-esq/2)

    const int tid = threadIdx.x;
    const int li  = tid & 15;
    const int g   = (tid >> 4) & 3;
    const int w   = tid >> 6;

    // X fragments fp16 (rows rowA, rowA+16) — 32 VGPR, const-indexed
    f16x8 xh[2][4];
    const size_t rowA = (size_t)blockIdx.x * 128 + w * 32 + li;
    #pragma unroll
    for (int rs = 0; rs < 2; ++rs) {
        const float* xp = x + (rowA + rs * 16) * DIM + g * 8;
        #pragma unroll
        for (int s = 0; s < 4; ++s) {
            float4 v0 = *(const float4*)(xp + s * 32);
            float4 v1 = *(const float4*)(xp + s * 32 + 4);
            f16x8 h;
            h[0] = (_Float16)v0.x; h[1] = (_Float16)v0.y;
            h[2] = (_Float16)v0.z; h[3] = (_Float16)v0.w;
            h[4] = (_Float16)v1.x; h[5] = (_Float16)v1.y;
            h[6] = (_Float16)v1.z; h[7] = (_Float16)v1.w;
            xh[rs][s] = h;
        }
    }

#define STAGE(stp_, buf_) do {                                                \
        const char* gE_ = (const char*)ehs_g + (size_t)(stp_) * 16384;        \
        char* lE_ = (char*)&ehb[buf_][0];                                     \
        _Pragma("unroll")                                                     \
        for (int j_ = 0; j_ < 4; ++j_) {                                      \
            int o_ = tid * 16 + j_ * 4096;                                    \
            GLDS(gE_ + o_, lE_ + o_);                                         \
        }                                                                     \
    } while (0)

    // ---- prologue: cinit + slab 0 ----
    GLDS((const char*)cinit_g + tid * 16, (char*)ci_lds + tid * 16);
    STAGE(0, 0);
    asm volatile("s_waitcnt vmcnt(0)" ::: "memory");
    __syncthreads();

    // hoisted per-lane LDS byte offsets (loop-invariant swizzle addressing)
    const int off0 = li * 256 + (((g + 0)  ^ li) << 4);
    const int off1 = li * 256 + (((g + 4)  ^ li) << 4);
    const int off2 = li * 256 + (((g + 8)  ^ li) << 4);
    const int off3 = li * 256 + (((g + 12) ^ li) << 4);

    // top-4 packed pair-keys per rowset, descending
    const float NEG = __uint_as_float(0xFF7FFE00u);   // ~-3.4e38, low 9 bits 0
    float s0[2], s1[2], s2[2], s3[2];
    #pragma unroll
    for (int rs = 0; rs < 2; ++rs) { s0[rs] = s1[rs] = s2[rs] = s3[rs] = NEG; }

    for (int stp = 0; stp < 16; ++stp) {     // 16 steps x 64 bins
        const int buf = stp & 1;
        if (stp < 15) STAGE(stp + 1, buf ^ 1);   // prefetch next 64-bin slab

        #pragma unroll
        for (int tl = 0; tl < 4; ++tl) {
            const char* bE = (const char*)&ehb[buf][0] + tl * 4096;
            const int binb = stp * 64 + tl * 16 + g * 4;   // quad base
            const f32x4 ci = *(const f32x4*)&ci_lds[binb];
            f16x8 e0 = *(const f16x8*)(bE + off0);
            f16x8 e1 = *(const f16x8*)(bE + off1);
            f16x8 e2 = *(const f16x8*)(bE + off2);
            f16x8 e3 = *(const f16x8*)(bE + off3);
            f32x4 aP0 = MFMA16(e0, xh[0][0], ci);
            f32x4 aP1 = MFMA16(e0, xh[1][0], ci);
            aP0 = MFMA16(e1, xh[0][1], aP0); aP1 = MFMA16(e1, xh[1][1], aP1);
            aP0 = MFMA16(e2, xh[0][2], aP0); aP1 = MFMA16(e2, xh[1][2], aP1);
            aP0 = MFMA16(e3, xh[0][3], aP0); aP1 = MFMA16(e3, xh[1][3], aP1);
            // fold: raw pair-max, pack 9-bit pair id, 2 sorted-inserts
            const int pid = binb >> 1;       // pair id of (binb, binb+1)
            {
                float q01 = packkey(fmaxf(aP0[0], aP0[1]), pid);
                float q23 = packkey(fmaxf(aP0[2], aP0[3]), pid + 1);
                SINS(q01, s0[0], s1[0], s2[0], s3[0]);
                SINS(q23, s0[0], s1[0], s2[0], s3[0]);
            }
            {
                float q01 = packkey(fmaxf(aP1[0], aP1[1]), pid);
                float q23 = packkey(fmaxf(aP1[2], aP1[3]), pid + 1);
                SINS(q01, s0[1], s1[1], s2[1], s3[1]);
                SINS(q23, s0[1], s1[1], s2[1], s3[1]);
            }
        }
        asm volatile("s_waitcnt vmcnt(0)" ::: "memory");
        __syncthreads();
    }
#undef STAGE

    // ---- merge the 4 k-groups (disjoint pair sets, same rows) ----
    #pragma unroll
    for (int mm = 16; mm <= 32; mm <<= 1) {
        #pragma unroll
        for (int rs = 0; rs < 2; ++rs) {
            float q0 = __shfl_xor(s0[rs], mm);
            float q1 = __shfl_xor(s1[rs], mm);
            float q2 = __shfl_xor(s2[rs], mm);
            float q3 = __shfl_xor(s3[rs], mm);
            SINS(q0, s0[rs], s1[rs], s2[rs], s3[rs]);
            SINS(q1, s0[rs], s1[rs], s2[rs], s3[rs]);
            SINS(q2, s0[rs], s1[rs], s2[rs], s3[rs]);
            SINS(q3, s0[rs], s1[rs], s2[rs], s3[rs]);
        }
    }
    if ((tid & 63) < 16) {
        #pragma unroll
        for (int rs = 0; rs < 2; ++rs) {
            const size_t r = rowA + rs * 16;
            // decode pair id -> pair base (even bin) — r12 rescore interface
            cand[r * 4 + 0] = (float)((__float_as_uint(s0[rs]) & 0x1FFu) << 1);
            cand[r * 4 + 1] = (float)((__float_as_uint(s1[rs]) & 0x1FFu) << 1);
            cand[r * 4 + 2] = (float)((__float_as_uint(s2[rs]) & 0x1FFu) << 1);
            cand[r * 4 + 3] = (float)((__float_as_uint(s3[rs]) & 0x1FFu) << 1);
        }
    }
}

// ---- rescore: exact fp32 on 4 pairs (8 bins); k split across 4 lanes ----
// Lane sub owns k-chunks (j*4+sub) -> every e/x load 64B-contiguous per
// 4-lane row-group. Butterfly shfl_xor sums bitwise lane-identical.
// Optionally fuses the gather (outq != nullptr).  [proven round 12]
__global__ __launch_bounds__(256) void vq_rescore(
    const float* __restrict__ x, const float* __restrict__ embed,
    const float* __restrict__ esq_g, const float* __restrict__ cand,
    float* __restrict__ ind_f, float4* __restrict__ outq)
{
    const int tid = threadIdx.x;
    const int sub = tid & 3;
    const size_t row = (size_t)blockIdx.x * 64 + (tid >> 2);

    const float4* xg = (const float4*)(x + row * DIM);
    float4 xq[8];
    #pragma unroll
    for (int j = 0; j < 8; ++j) xq[j] = xg[j * 4 + sub];   // 64B/row-group

    float xs = 0.f;
    #pragma unroll
    for (int j = 0; j < 8; ++j) {
        float4 v = xq[j];
        xs = fmaf(v.x, v.x, xs); xs = fmaf(v.y, v.y, xs);
        xs = fmaf(v.z, v.z, xs); xs = fmaf(v.w, v.w, xs);
    }
    xs += __shfl_xor(xs, 1);
    xs += __shfl_xor(xs, 2);

    const float4 qv = *(const float4*)&cand[row * 4];
    const int qb0 = (int)qv.x, qb1 = (int)qv.y, qb2 = (int)qv.z, qb3 = (int)qv.w;

    const float4* e4 = (const float4*)embed;
    f32x4 acc[8];
    #pragma unroll
    for (int c = 0; c < 8; ++c) acc[c] = f32x4{0.f,0.f,0.f,0.f};
    #pragma unroll
    for (int c = 0; c < 8; ++c) {           // all 64 loads independent
        const int bin = (c < 2 ? qb0 : c < 4 ? qb1 : c < 6 ? qb2 : qb3) + (c & 1);
        #pragma unroll
        for (int j = 0; j < 8; ++j) {
            float4 ev = e4[(size_t)bin * 32 + j * 4 + sub];
            float4 xv = xq[j];
            acc[c][0] = fmaf(xv.x, ev.x, acc[c][0]);
            acc[c][1] = fmaf(xv.y, ev.y, acc[c][1]);
            acc[c][2] = fmaf(xv.z, ev.z, acc[c][2]);
            acc[c][3] = fmaf(xv.w, ev.w, acc[c][3]);
        }
    }
    float bd = -3.402823466e38f;
    int   bb = 0x7FFFFFFF;
    #pragma unroll
    for (int c = 0; c < 8; ++c) {
        const int bin = (c < 2 ? qb0 : c < 4 ? qb1 : c < 6 ? qb2 : qb3) + (c & 1);
        float p = (acc[c][0] + acc[c][1]) + (acc[c][2] + acc[c][3]);
        p += __shfl_xor(p, 1);
        p += __shfl_xor(p, 2);               // full dot, lane-identical
        float d = -(fmaf(-2.f, p, xs) + esq_g[bin]);   // round-1 expression
        if (d > bd || (d == bd && bin < bb)) { bd = d; bb = bin; }
    }
    if (sub == 0) ind_f[row] = (float)bb;
    if (outq) {                              // fused gather (all lanes agree on bb)
        #pragma unroll
        for (int j = 0; j < 8; ++j)
            outq[row * 32 + j * 4 + sub] = e4[(size_t)bb * 32 + j * 4 + sub];
    }
}

// ---- gather (fallback path only): quantize = embed[ind] ----
__global__ __launch_bounds__(256) void vq_gather(
    const float* __restrict__ embed,
    const float* __restrict__ ind_f,
    float4* __restrict__ out)
{
    int i   = blockIdx.x * 256 + threadIdx.x;   // over N*DIM/4
    int row = i >> 5;                           // DIM/4 == 32
    int k   = i & 31;
    int b   = (int)ind_f[row];
    out[i] = reinterpret_cast<const float4*>(embed)[b * (DIM / 4) + k];
}

extern "C" void kernel_launch(void* const* d_in, const int* in_sizes, int n_in,
                              void* d_out, int out_size, void* d_ws, size_t ws_size,
                              hipStream_t stream) {
    const float* x     = (const float*)d_in[0];   // [N, 128] fp32
    const float* embed = (const float*)d_in[1];   // [1024, 128] fp32
    float* out = (float*)d_out;

    const int N = in_sizes[0] / DIM;              // 262144
    float* ind_f = out + (size_t)N * DIM;         // output 1 (indices as float)

    const bool use_ws = ws_size >= ((size_t)6 << 20);   // 4.27 MB needed
    _Float16* ehs; float* esq_g; float* cinit_g; float* cand;
    if (use_ws) {                                 // scratch fully in d_ws
        char* wb = (char*)d_ws;
        ehs     = (_Float16*)wb;                  // 256 KB
        esq_g   = (float*)(wb + (256u << 10));    // 4 KB
        cinit_g = (float*)(wb + (260u << 10));    // 4 KB
        cand    = (float*)(wb + (512u << 10));    // 4 MB
    } else {                                      // proven in-out layout
        char* ob = (char*)d_out;
        cand    = out;                            // [N][4] floats (4 MB)
        ehs     = (_Float16*)(ob + (32u << 20));
        esq_g   = (float*)(ob + (36u << 20));
        cinit_g = (float*)(ob + (36u << 20) + 4096);
    }

    vq_prep<<<BINS / 256, 256, 0, stream>>>(embed, ehs, esq_g, cinit_g);
    vq_stage_a<<<N / 128, 256, 0, stream>>>(x, ehs, cinit_g, cand);
    vq_rescore<<<N / 64, 256, 0, stream>>>(x, embed, esq_g, cand, ind_f,
                                           use_ws ? (float4*)out : nullptr);
    if (!use_ws)
        vq_gather<<<(N * (DIM / 4)) / 256, 256, 0, stream>>>(embed, ind_f, (float4*)out);
}

// Round 17
// 187.333 us; speedup vs baseline: 1.0142x; 1.0093x over previous
//
#include <hip/hip_runtime.h>

#define DIM  128
#define BINS 1024

typedef __attribute__((ext_vector_type(8))) _Float16 f16x8;
typedef __attribute__((ext_vector_type(4))) float f32x4;

#define MFMA16(a, b, c) __builtin_amdgcn_mfma_f32_16x16x32_f16(a, b, c, 0, 0, 0)

#define GLDS(gp, lp) __builtin_amdgcn_global_load_lds(                        \
    (const __attribute__((address_space(1))) void*)(gp),                     \
    (__attribute__((address_space(3))) void*)(lp), 16, 0, 0)

// guaranteed single-instruction v_med3_f32
__device__ __forceinline__ float med3a(float a, float b, float c) {
    float r;
    asm("v_med3_f32 %0, %1, %2, %3" : "=v"(r) : "v"(a), "v"(b), "v"(c));
    return r;
}

// (key & ~0x1FF) | pair_id  — single v_and_or_b32
__device__ __forceinline__ float packkey(float k, int pid) {
    float r;
    asm("v_and_or_b32 %0, %1, %2, %3"
        : "=v"(r) : "v"(k), "s"(0xFFFFFE00u), "v"(pid));
    return r;
}

// sorted-insert x into descending (S0>=S1>=S2>=S3): 1 max + 3 med3, depth 2
#define SINS(x, S0, S1, S2, S3) do {                                          \
        float n0_ = fmaxf(S0, (x));                                           \
        float n1_ = med3a((x), S0, S1);                                       \
        float n2_ = med3a((x), S1, S2);                                       \
        float n3_ = med3a((x), S2, S3);                                       \
        S0 = n0_; S1 = n1_; S2 = n2_; S3 = n3_;                               \
    } while (0)

// ---- prep: esq (round-1 1-chain fmaf), cinit = -esq/2, E -> swizzled fp16 ----
__global__ __launch_bounds__(256) void vq_prep(
    const float* __restrict__ embed, _Float16* __restrict__ ehs,
    float* __restrict__ esq_g, float* __restrict__ cinit_g)
{
    int b = blockIdx.x * 256 + threadIdx.x;  // grid exactly BINS/256
    const float* e = embed + (size_t)b * DIM;
    float s = 0.f;
    #pragma unroll
    for (int k = 0; k < DIM; ++k) s = fmaf(e[k], e[k], s);
    esq_g[b] = s;
    cinit_g[b] = -0.5f * s;                  // MFMA C-init: key = dot - esq/2
    #pragma unroll
    for (int c = 0; c < 16; ++c) {          // 16B chunks of the fp16 row
        int slot = c ^ (b & 15);            // XOR-swizzle baked into storage
        #pragma unroll
        for (int j = 0; j < 8; ++j)
            ehs[b * 128 + slot * 8 + j] = (_Float16)e[c * 8 + j];   // RNE
    }
}

// ---- stage A: 1-term fp16 MFMA (C-init = -esq/2) + top-4 PAIR candidates ----
// r14/r16 structure; 16-step loop FULLY UNROLLED: buf/binb/pid/LDS bases all
// compile-time -> immediate-offset ds_reads, no per-step select/address VALU.
__global__ __launch_bounds__(256) void vq_stage_a(
    const float* __restrict__ x,
    const _Float16* __restrict__ ehs_g,
    const float* __restrict__ cinit_g,
    float* __restrict__ cand)               // [N][4] candidate PAIR bases
{
    __shared__ _Float16 ehb[2][8192];       // 2 x 16 KB (64 bins x 128 fp16)
    __shared__ float ci_lds[BINS];          // 4 KB (-esq/2)

    const int tid = threadIdx.x;
    const int li  = tid & 15;
    const int g   = (tid >> 4) & 3;
    const int w   = tid >> 6;

    // X fragments fp16 (rows rowA, rowA+16) — 32 VGPR, const-indexed
    f16x8 xh[2][4];
    const size_t rowA = (size_t)blockIdx.x * 128 + w * 32 + li;
    #pragma unroll
    for (int rs = 0; rs < 2; ++rs) {
        const float* xp = x + (rowA + rs * 16) * DIM + g * 8;
        #pragma unroll
        for (int s = 0; s < 4; ++s) {
            float4 v0 = *(const float4*)(xp + s * 32);
            float4 v1 = *(const float4*)(xp + s * 32 + 4);
            f16x8 h;
            h[0] = (_Float16)v0.x; h[1] = (_Float16)v0.y;
            h[2] = (_Float16)v0.z; h[3] = (_Float16)v0.w;
            h[4] = (_Float16)v1.x; h[5] = (_Float16)v1.y;
            h[6] = (_Float16)v1.z; h[7] = (_Float16)v1.w;
            xh[rs][s] = h;
        }
    }

#define STAGE(stp_, buf_) do {                                                \
        const char* gE_ = (const char*)ehs_g + (size_t)(stp_) * 16384;        \
        char* lE_ = (char*)&ehb[buf_][0];                                     \
        _Pragma("unroll")                                                     \
        for (int j_ = 0; j_ < 4; ++j_) {                                      \
            int o_ = tid * 16 + j_ * 4096;                                    \
            GLDS(gE_ + o_, lE_ + o_);                                         \
        }                                                                     \
    } while (0)

    // ---- prologue: cinit + slab 0 ----
    GLDS((const char*)cinit_g + tid * 16, (char*)ci_lds + tid * 16);
    STAGE(0, 0);
    asm volatile("s_waitcnt vmcnt(0)" ::: "memory");
    __syncthreads();

    // hoisted per-lane LDS byte offsets (loop-invariant swizzle addressing)
    const int off0 = li * 256 + (((g + 0)  ^ li) << 4);
    const int off1 = li * 256 + (((g + 4)  ^ li) << 4);
    const int off2 = li * 256 + (((g + 8)  ^ li) << 4);
    const int off3 = li * 256 + (((g + 12) ^ li) << 4);

    // top-4 packed pair-keys per rowset, descending
    const float NEG = __uint_as_float(0xFF7FFE00u);   // ~-3.4e38, low 9 bits 0
    float s0[2], s1[2], s2[2], s3[2];
    #pragma unroll
    for (int rs = 0; rs < 2; ++rs) { s0[rs] = s1[rs] = s2[rs] = s3[rs] = NEG; }

    #pragma unroll                            // FULL unroll: 16 steps
    for (int stp = 0; stp < 16; ++stp) {     // 16 steps x 64 bins
        const int buf = stp & 1;             // compile-time after unroll
        if (stp < 15) STAGE(stp + 1, buf ^ 1);   // prefetch next 64-bin slab

        #pragma unroll
        for (int tl = 0; tl < 4; ++tl) {
            const char* bE = (const char*)&ehb[buf][0] + tl * 4096;
            const int binb = stp * 64 + tl * 16 + g * 4;   // quad base
            const f32x4 ci = *(const f32x4*)&ci_lds[binb];
            f16x8 e0 = *(const f16x8*)(bE + off0);
            f16x8 e1 = *(const f16x8*)(bE + off1);
            f16x8 e2 = *(const f16x8*)(bE + off2);
            f16x8 e3 = *(const f16x8*)(bE + off3);
            f32x4 aP0 = MFMA16(e0, xh[0][0], ci);
            f32x4 aP1 = MFMA16(e0, xh[1][0], ci);
            aP0 = MFMA16(e1, xh[0][1], aP0); aP1 = MFMA16(e1, xh[1][1], aP1);
            aP0 = MFMA16(e2, xh[0][2], aP0); aP1 = MFMA16(e2, xh[1][2], aP1);
            aP0 = MFMA16(e3, xh[0][3], aP0); aP1 = MFMA16(e3, xh[1][3], aP1);
            // fold: raw pair-max, pack 9-bit pair id, 2 sorted-inserts
            const int pid = binb >> 1;       // pair id of (binb, binb+1)
            {
                float q01 = packkey(fmaxf(aP0[0], aP0[1]), pid);
                float q23 = packkey(fmaxf(aP0[2], aP0[3]), pid + 1);
                SINS(q01, s0[0], s1[0], s2[0], s3[0]);
                SINS(q23, s0[0], s1[0], s2[0], s3[0]);
            }
            {
                float q01 = packkey(fmaxf(aP1[0], aP1[1]), pid);
                float q23 = packkey(fmaxf(aP1[2], aP1[3]), pid + 1);
                SINS(q01, s0[1], s1[1], s2[1], s3[1]);
                SINS(q23, s0[1], s1[1], s2[1], s3[1]);
            }
        }
        asm volatile("s_waitcnt vmcnt(0)" ::: "memory");
        __syncthreads();
    }
#undef STAGE

    // ---- merge the 4 k-groups (disjoint pair sets, same rows) ----
    #pragma unroll
    for (int mm = 16; mm <= 32; mm <<= 1) {
        #pragma unroll
        for (int rs = 0; rs < 2; ++rs) {
            float q0 = __shfl_xor(s0[rs], mm);
            float q1 = __shfl_xor(s1[rs], mm);
            float q2 = __shfl_xor(s2[rs], mm);
            float q3 = __shfl_xor(s3[rs], mm);
            SINS(q0, s0[rs], s1[rs], s2[rs], s3[rs]);
            SINS(q1, s0[rs], s1[rs], s2[rs], s3[rs]);
            SINS(q2, s0[rs], s1[rs], s2[rs], s3[rs]);
            SINS(q3, s0[rs], s1[rs], s2[rs], s3[rs]);
        }
    }
    if ((tid & 63) < 16) {
        #pragma unroll
        for (int rs = 0; rs < 2; ++rs) {
            const size_t r = rowA + rs * 16;
            // decode pair id -> pair base (even bin) — r12 rescore interface
            cand[r * 4 + 0] = (float)((__float_as_uint(s0[rs]) & 0x1FFu) << 1);
            cand[r * 4 + 1] = (float)((__float_as_uint(s1[rs]) & 0x1FFu) << 1);
            cand[r * 4 + 2] = (float)((__float_as_uint(s2[rs]) & 0x1FFu) << 1);
            cand[r * 4 + 3] = (float)((__float_as_uint(s3[rs]) & 0x1FFu) << 1);
        }
    }
}

// ---- rescore: exact fp32 on 4 pairs (8 bins); k split across 4 lanes ----
// Lane sub owns k-chunks (j*4+sub) -> every e/x load 64B-contiguous per
// 4-lane row-group. Butterfly shfl_xor sums bitwise lane-identical.
// Optionally fuses the gather (outq != nullptr).  [proven round 12]
__global__ __launch_bounds__(256) void vq_rescore(
    const float* __restrict__ x, const float* __restrict__ embed,
    const float* __restrict__ esq_g, const float* __restrict__ cand,
    float* __restrict__ ind_f, float4* __restrict__ outq)
{
    const int tid = threadIdx.x;
    const int sub = tid & 3;
    const size_t row = (size_t)blockIdx.x * 64 + (tid >> 2);

    const float4* xg = (const float4*)(x + row * DIM);
    float4 xq[8];
    #pragma unroll
    for (int j = 0; j < 8; ++j) xq[j] = xg[j * 4 + sub];   // 64B/row-group

    float xs = 0.f;
    #pragma unroll
    for (int j = 0; j < 8; ++j) {
        float4 v = xq[j];
        xs = fmaf(v.x, v.x, xs); xs = fmaf(v.y, v.y, xs);
        xs = fmaf(v.z, v.z, xs); xs = fmaf(v.w, v.w, xs);
    }
    xs += __shfl_xor(xs, 1);
    xs += __shfl_xor(xs, 2);

    const float4 qv = *(const float4*)&cand[row * 4];
    const int qb0 = (int)qv.x, qb1 = (int)qv.y, qb2 = (int)qv.z, qb3 = (int)qv.w;

    const float4* e4 = (const float4*)embed;
    f32x4 acc[8];
    #pragma unroll
    for (int c = 0; c < 8; ++c) acc[c] = f32x4{0.f,0.f,0.f,0.f};
    #pragma unroll
    for (int c = 0; c < 8; ++c) {           // all 64 loads independent
        const int bin = (c < 2 ? qb0 : c < 4 ? qb1 : c < 6 ? qb2 : qb3) + (c & 1);
        #pragma unroll
        for (int j = 0; j < 8; ++j) {
            float4 ev = e4[(size_t)bin * 32 + j * 4 + sub];
            float4 xv = xq[j];
            acc[c][0] = fmaf(xv.x, ev.x, acc[c][0]);
            acc[c][1] = fmaf(xv.y, ev.y, acc[c][1]);
            acc[c][2] = fmaf(xv.z, ev.z, acc[c][2]);
            acc[c][3] = fmaf(xv.w, ev.w, acc[c][3]);
        }
    }
    float bd = -3.402823466e38f;
    int   bb = 0x7FFFFFFF;
    #pragma unroll
    for (int c = 0; c < 8; ++c) {
        const int bin = (c < 2 ? qb0 : c < 4 ? qb1 : c < 6 ? qb2 : qb3) + (c & 1);
        float p = (acc[c][0] + acc[c][1]) + (acc[c][2] + acc[c][3]);
        p += __shfl_xor(p, 1);
        p += __shfl_xor(p, 2);               // full dot, lane-identical
        float d = -(fmaf(-2.f, p, xs) + esq_g[bin]);   // round-1 expression
        if (d > bd || (d == bd && bin < bb)) { bd = d; bb = bin; }
    }
    if (sub == 0) ind_f[row] = (float)bb;
    if (outq) {                              // fused gather (all lanes agree on bb)
        #pragma unroll
        for (int j = 0; j < 8; ++j)
            outq[row * 32 + j * 4 + sub] = e4[(size_t)bb * 32 + j * 4 + sub];
    }
}

// ---- gather (fallback path only): quantize = embed[ind] ----
__global__ __launch_bounds__(256) void vq_gather(
    const float* __restrict__ embed,
    const float* __restrict__ ind_f,
    float4* __restrict__ out)
{
    int i   = blockIdx.x * 256 + threadIdx.x;   // over N*DIM/4
    int row = i >> 5;                           // DIM/4 == 32
    int k   = i & 31;
    int b   = (int)ind_f[row];
    out[i] = reinterpret_cast<const float4*>(embed)[b * (DIM / 4) + k];
}

extern "C" void kernel_launch(void* const* d_in, const int* in_sizes, int n_in,
                              void* d_out, int out_size, void* d_ws, size_t ws_size,
                              hipStream_t stream) {
    const float* x     = (const float*)d_in[0];   // [N, 128] fp32
    const float* embed = (const float*)d_in[1];   // [1024, 128] fp32
    float* out = (float*)d_out;

    const int N = in_sizes[0] / DIM;              // 262144
    float* ind_f = out + (size_t)N * DIM;         // output 1 (indices as float)

    const bool use_ws = ws_size >= ((size_t)6 << 20);   // 4.27 MB needed
    _Float16* ehs; float* esq_g; float* cinit_g; float* cand;
    if (use_ws) {                                 // scratch fully in d_ws
        char* wb = (char*)d_ws;
        ehs     = (_Float16*)wb;                  // 256 KB
        esq_g   = (float*)(wb + (256u << 10));    // 4 KB
        cinit_g = (float*)(wb + (260u << 10));    // 4 KB
        cand    = (float*)(wb + (512u << 10));    // 4 MB
    } else {                                      // proven in-out layout
        char* ob = (char*)d_out;
        cand    = out;                            // [N][4] floats (4 MB)
        ehs     = (_Float16*)(ob + (32u << 20));
        esq_g   = (float*)(ob + (36u << 20));
        cinit_g = (float*)(ob + (36u << 20) + 4096);
    }

    vq_prep<<<BINS / 256, 256, 0, stream>>>(embed, ehs, esq_g, cinit_g);
    vq_stage_a<<<N / 128, 256, 0, stream>>>(x, ehs, cinit_g, cand);
    vq_rescore<<<N / 64, 256, 0, stream>>>(x, embed, esq_g, cand, ind_f,
                                           use_ws ? (float4*)out : nullptr);
    if (!use_ws)
        vq_gather<<<(N * (DIM / 4)) / 256, 256, 0, stream>>>(embed, ind_f, (float4*)out);
}